// Round 4
// baseline (227.322 us; speedup 1.0000x reference)
//
#include <hip/hip_runtime.h>

#define D     512
#define HW    (D * D)
#define BLOCK 256

// Shared weight/clip/oob math — identical f32 ops to the reference.
__device__ __forceinline__ void weights_oob(float rx, float ry,
    float& w00, float& w10, float& w01, float& w11,
    float& cxq, float& cyq, float* oob)
{
    cxq = fminf(fmaxf(rx, 0.001f), 510.999f);
    cyq = fminf(fmaxf(ry, 0.001f), 510.999f);
    float dx = rx - cxq, dy = ry - cyq;
    *oob += dx * dx + dy * dy;
    float xf = floorf(cxq), xc = ceilf(cxq);
    float yf = floorf(cyq), yc = ceilf(cyq);
    float wxf = 1.0f - (cxq - xf), wxc = 1.0f - (xc - cxq);
    float wyf = 1.0f - (cyq - yf), wyc = 1.0f - (yc - cyq);
    w00 = wxf * wyf; w10 = wxc * wyf; w01 = wxf * wyc; w11 = wxc * wyc;
}

// General path: per-lane gathers (ind = y + D*x per reference).
__device__ __forceinline__ void samp_gather(const float* __restrict__ im,
    float rx, float ry, float m, float r3[3], float* oob)
{
    float w00, w10, w01, w11, cxq, cyq;
    weights_oob(rx, ry, w00, w10, w01, w11, cxq, cyq, oob);
    int xf = (int)cxq, yf = (int)cyq;              // floor (coords >= 0)
    int xc = (int)ceilf(cxq), yc = (int)ceilf(cyq);
    int i00 = yf + D * xf, i10 = yf + D * xc;
    int i01 = yc + D * xf, i11 = yc + D * xc;
#pragma unroll
    for (int c = 0; c < 3; ++c) {
        const float* __restrict__ ch = im + (size_t)c * HW;
        r3[c] += m * (w00 * ch[i00] + w10 * ch[i10] + w01 * ch[i01] + w11 * ch[i11]);
    }
}

// Corner fast path: pixel values {510,511}^2 supplied (block-uniform, SGPRs).
// Valid whenever all clipped coords lie in (510, 511) — guaranteed by caller.
__device__ __forceinline__ void samp_corner(const float* __restrict__ cp,
    float rx, float ry, float m, float r3[3], float* oob)
{
    float w00, w10, w01, w11, cxq, cyq;
    weights_oob(rx, ry, w00, w10, w01, w11, cxq, cyq, oob);
#pragma unroll
    for (int c = 0; c < 3; ++c)
        r3[c] += m * (w00 * cp[c * 4 + 0] + w10 * cp[c * 4 + 1]
                    + w01 * cp[c * 4 + 2] + w11 * cp[c * 4 + 3]);
}

__global__ void __launch_bounds__(BLOCK) vm_kernel(
    const float* __restrict__ im1, const float* __restrict__ im2,
    const float* __restrict__ C,   const float* __restrict__ M1,
    const float* __restrict__ M2,  float* __restrict__ out,
    double* __restrict__ partials, int nblk_a)
{
    float oob = 0.0f;
    int b = blockIdx.x;

    if (b < nblk_a) {
        // ---------------- interior role: j in [8,512), 8 px/thread ----------
        int n  = b >> 7;                 // 128 row-groups per n
        int rg = b & 127;
        int r  = threadIdx.x >> 6;       // row within block (4 rows/block)
        int l  = threadIdx.x & 63;       // lane
        int i  = rg * 4 + r;
        bool active = (l < 63);          // 63 lanes x 8 px = 504 cols (8..511)
        int j0 = 8 + l * 8;

        const float* base1 = im1 + (size_t)n * 3 * HW;
        const float* base2 = im2 + (size_t)n * 3 * HW;

        // corner 2x2 pixel values — block-uniform addresses -> scalar loads
        float cp1[12], cp2[12];
#pragma unroll
        for (int c = 0; c < 3; ++c) {
            const float* c1 = base1 + (size_t)c * HW;
            const float* c2 = base2 + (size_t)c * HW;
            cp1[c*4+0] = c1[510 + D*510]; cp1[c*4+1] = c1[510 + D*511];
            cp1[c*4+2] = c1[511 + D*510]; cp1[c*4+3] = c1[511 + D*511];
            cp2[c*4+0] = c2[510 + D*510]; cp2[c*4+1] = c2[510 + D*511];
            cp2[c*4+2] = c2[511 + D*510]; cp2[c*4+3] = c2[511 + D*511];
        }

        size_t cb = (size_t)n * 2 * HW, mb = (size_t)n * HW, ob = (size_t)n * 3 * HW;
        size_t row = (size_t)i * D + j0;

        float cx[8], cy[8], m1n[8], m2n[8];
        bool lane_bad = false;
        if (active) {
            // 8 independent dwordx4 loads — max MLP
            float4 cxa = *(const float4*)(C  + cb + row);
            float4 cxb = *(const float4*)(C  + cb + row + 4);
            float4 cya = *(const float4*)(C  + cb + HW + row);
            float4 cyb = *(const float4*)(C  + cb + HW + row + 4);
            float4 m1a = *(const float4*)(M1 + mb + row);
            float4 m1b = *(const float4*)(M1 + mb + row + 4);
            float4 m2a = *(const float4*)(M2 + mb + row);
            float4 m2b = *(const float4*)(M2 + mb + row + 4);
            cx[0]=cxa.x; cx[1]=cxa.y; cx[2]=cxa.z; cx[3]=cxa.w;
            cx[4]=cxb.x; cx[5]=cxb.y; cx[6]=cxb.z; cx[7]=cxb.w;
            cy[0]=cya.x; cy[1]=cya.y; cy[2]=cya.z; cy[3]=cya.w;
            cy[4]=cyb.x; cy[5]=cyb.y; cy[6]=cyb.z; cy[7]=cyb.w;
            float m1v[8] = {m1a.x,m1a.y,m1a.z,m1a.w,m1b.x,m1b.y,m1b.z,m1b.w};
            float m2v[8] = {m2a.x,m2a.y,m2a.z,m2a.w,m2b.x,m2b.y,m2b.z,m2b.w};
            float fi = (float)i;
#pragma unroll
            for (int k = 0; k < 8; ++k) {
                float tot = m1v[k] + m2v[k];
                m1n[k] = m1v[k] / tot;
                m2n[k] = m2v[k] / tot;
                // exact min over both directions: (fi - |cx|) == min(fi+cx, fi-cx)
                float mx = (fi - fabsf(cx[k])) * 512.0f;
                float my = ((float)(j0 + k) - fabsf(cy[k])) * 512.0f;
                lane_bad |= (mx < 510.5f) || (my < 510.5f);
            }
        } else {
#pragma unroll
            for (int k = 0; k < 8; ++k) { cx[k]=0.f; cy[k]=0.f; m1n[k]=0.f; m2n[k]=0.f; }
        }

        unsigned long long bad = __ballot(lane_bad);
        float a0[8], a1[8], a2[8];
#pragma unroll
        for (int k = 0; k < 8; ++k) { a0[k]=0.f; a1[k]=0.f; a2[k]=0.f; }
        float fi = (float)i;

        if (bad == 0ULL) {
            if (active) {
#pragma unroll
                for (int k = 0; k < 8; ++k) {
                    float fj = (float)(j0 + k);
                    float r3[3] = {0.f, 0.f, 0.f};
                    samp_corner(cp1, (fi + cx[k]) * 512.0f, (fj + cy[k]) * 512.0f, m1n[k], r3, &oob);
                    samp_corner(cp2, (fi - cx[k]) * 512.0f, (fj - cy[k]) * 512.0f, m2n[k], r3, &oob);
                    a0[k] = r3[0]; a1[k] = r3[1]; a2[k] = r3[2];
                }
            }
        } else {
            if (active) {
#pragma unroll
                for (int k = 0; k < 8; ++k) {
                    float fj = (float)(j0 + k);
                    float r3[3] = {0.f, 0.f, 0.f};
                    samp_gather(base1, (fi + cx[k]) * 512.0f, (fj + cy[k]) * 512.0f, m1n[k], r3, &oob);
                    samp_gather(base2, (fi - cx[k]) * 512.0f, (fj - cy[k]) * 512.0f, m2n[k], r3, &oob);
                    a0[k] = r3[0]; a1[k] = r3[1]; a2[k] = r3[2];
                }
            }
        }

        if (active) {
            *(float4*)(out + ob + row)            = make_float4(a0[0],a0[1],a0[2],a0[3]);
            *(float4*)(out + ob + row + 4)        = make_float4(a0[4],a0[5],a0[6],a0[7]);
            *(float4*)(out + ob + HW + row)       = make_float4(a1[0],a1[1],a1[2],a1[3]);
            *(float4*)(out + ob + HW + row + 4)   = make_float4(a1[4],a1[5],a1[6],a1[7]);
            *(float4*)(out + ob + 2*HW + row)     = make_float4(a2[0],a2[1],a2[2],a2[3]);
            *(float4*)(out + ob + 2*HW + row + 4) = make_float4(a2[4],a2[5],a2[6],a2[7]);
        }
    } else {
        // ---------------- boundary role: j in [0,8), 1 px/thread ------------
        int t = (b - nblk_a) * BLOCK + threadIdx.x;
        int n   = t >> 12;              // 8 cols * 512 rows = 4096 px per n
        int rem = t & 4095;
        int i = rem >> 3, j = rem & 7;
        const float* base1 = im1 + (size_t)n * 3 * HW;
        const float* base2 = im2 + (size_t)n * 3 * HW;
        size_t cb = (size_t)n * 2 * HW, mb = (size_t)n * HW, ob = (size_t)n * 3 * HW;
        size_t pp = (size_t)i * D + j;

        float cxv = C[cb + pp], cyv = C[cb + HW + pp];
        float m1v = M1[mb + pp], m2v = M2[mb + pp];
        float tot = m1v + m2v;
        float m1nv = m1v / tot, m2nv = m2v / tot;
        float r3[3] = {0.f, 0.f, 0.f};
        float fi = (float)i, fj = (float)j;
        samp_gather(base1, (fi + cxv) * 512.0f, (fj + cyv) * 512.0f, m1nv, r3, &oob);
        samp_gather(base2, (fi - cxv) * 512.0f, (fj - cyv) * 512.0f, m2nv, r3, &oob);
        out[ob + pp]          = r3[0];
        out[ob + HW + pp]     = r3[1];
        out[ob + 2 * HW + pp] = r3[2];
    }

    // ---- block reduction of oob (f32 in-wave, f64 across) -> 1 store/block --
    for (int off = 32; off > 0; off >>= 1)
        oob += __shfl_down(oob, off, 64);

    __shared__ float soob[BLOCK / 64];
    int lane = threadIdx.x & 63;
    int w    = threadIdx.x >> 6;
    if (lane == 0) soob[w] = oob;
    __syncthreads();
    if (threadIdx.x == 0)
        partials[blockIdx.x] = (double)soob[0] + (double)soob[1]
                             + (double)soob[2] + (double)soob[3];
}

__global__ void __launch_bounds__(BLOCK) reduce_kernel(
    const double* __restrict__ partials, int nparts,
    float* __restrict__ out_last, double scale)
{
    double s = 0.0;
    for (int i = threadIdx.x; i < nparts; i += BLOCK)
        s += partials[i];
    for (int off = 32; off > 0; off >>= 1)
        s += __shfl_down(s, off, 64);

    __shared__ double sm[BLOCK / 64];
    int lane = threadIdx.x & 63;
    int w    = threadIdx.x >> 6;
    if (lane == 0) sm[w] = s;
    __syncthreads();
    if (threadIdx.x == 0)
        *out_last = (float)((sm[0] + sm[1] + sm[2] + sm[3]) * scale);
}

extern "C" void kernel_launch(void* const* d_in, const int* in_sizes, int n_in,
                              void* d_out, int out_size, void* d_ws, size_t ws_size,
                              hipStream_t stream) {
    const float* im1 = (const float*)d_in[0];
    const float* im2 = (const float*)d_in[1];
    const float* C   = (const float*)d_in[2];
    const float* M1  = (const float*)d_in[3];
    const float* M2  = (const float*)d_in[4];
    float* out = (float*)d_out;
    double* ws = (double*)d_ws;

    int N = in_sizes[3] / HW;                 // M1 is [N,1,H,W]
    int nblk_a = N * 128;                     // interior: 4 rows x 504 cols / block
    int nblk_b = N * 16;                      // boundary: 8 cols, 1 px/thread
    int blocks = nblk_a + nblk_b;             // 2304 for N=16

    vm_kernel<<<blocks, BLOCK, 0, stream>>>(im1, im2, C, M1, M2, out, ws, nblk_a);

    // loss = sum / (N*2*HW) / D^2 * 1e-4  (a and b share the mean count)
    double scale = 1.0 / ((double)N * 2.0 * (double)HW) / (double)HW * 1e-4;
    reduce_kernel<<<1, BLOCK, 0, stream>>>(ws, blocks, out + (out_size - 1), scale);
}

// Round 5
// 200.464 us; speedup vs baseline: 1.1340x; 1.1340x over previous
//
#include <hip/hip_runtime.h>

#define D     512
#define HW    (D * D)
#define BLOCK 256

// General path: full reference bilinear with per-lane gathers (ind = y + D*x).
__device__ __forceinline__ void samp_gather(const float* __restrict__ im,
    float rx, float ry, float m, float r3[3], float* oob)
{
    float cxq = fminf(fmaxf(rx, 0.001f), 510.999f);
    float cyq = fminf(fmaxf(ry, 0.001f), 510.999f);
    float dx = rx - cxq, dy = ry - cyq;
    *oob += dx * dx + dy * dy;
    float xff = floorf(cxq), xcf = ceilf(cxq);
    float yff = floorf(cyq), ycf = ceilf(cyq);
    float wxf = 1.0f - (cxq - xff), wxc = 1.0f - (xcf - cxq);
    float wyf = 1.0f - (cyq - yff), wyc = 1.0f - (ycf - cyq);
    float w00 = wxf * wyf, w10 = wxc * wyf, w01 = wxf * wyc, w11 = wxc * wyc;
    int xf = (int)xff, xc = (int)xcf, yf = (int)yff, yc = (int)ycf;
    int i00 = yf + D * xf, i10 = yf + D * xc;
    int i01 = yc + D * xf, i11 = yc + D * xc;
#pragma unroll
    for (int c = 0; c < 3; ++c) {
        const float* __restrict__ ch = im + (size_t)c * HW;
        r3[c] += m * (w00 * ch[i00] + w10 * ch[i10] + w01 * ch[i01] + w11 * ch[i11]);
    }
}

__global__ void __launch_bounds__(BLOCK) vm_kernel(
    const float* __restrict__ im1, const float* __restrict__ im2,
    const float* __restrict__ C,   const float* __restrict__ M1,
    const float* __restrict__ M2,  float* __restrict__ out,
    double* __restrict__ partials)
{
    int b = blockIdx.x;
    int n = b >> 9;                  // one image row per block
    int i = b & (D - 1);
    int j0 = threadIdx.x * 2;

    const float* base1 = im1 + (size_t)n * 3 * HW;
    const float* base2 = im2 + (size_t)n * 3 * HW;

    // When a sample fully clips high, clipped coord == 510.999f (constant) so
    // bilinear weights are constants and the sample value is block-uniform:
    //   S = WF*WF*p(510,510) + WC*WF*p(x=511,y=510) + WF*WC*p(510,511) + WC*WC*p(511,511)
    // (exact f32 replication of reference weight arithmetic)
    const float WF = 1.0f - (510.999f - 510.0f);   // x/y-floor weight
    const float WC = 1.0f - (511.0f - 510.999f);   // x/y-ceil  weight
    float S1[3], S2[3];
#pragma unroll
    for (int c = 0; c < 3; ++c) {
        const float* c1 = base1 + (size_t)c * HW;
        const float* c2 = base2 + (size_t)c * HW;
        S1[c] = (WF * WF) * c1[510 + D * 510] + (WC * WF) * c1[510 + D * 511]
              + (WF * WC) * c1[511 + D * 510] + (WC * WC) * c1[511 + D * 511];
        S2[c] = (WF * WF) * c2[510 + D * 510] + (WC * WF) * c2[510 + D * 511]
              + (WF * WC) * c2[511 + D * 510] + (WC * WC) * c2[511 + D * 511];
    }

    size_t cb = (size_t)n * 2 * HW, mb = (size_t)n * HW, ob = (size_t)n * 3 * HW;
    size_t pp = (size_t)i * D + j0;

    float2 cx2 = *(const float2*)(C  + cb + pp);
    float2 cy2 = *(const float2*)(C  + cb + HW + pp);
    float2 m12 = *(const float2*)(M1 + mb + pp);
    float2 m22 = *(const float2*)(M2 + mb + pp);

    float fi = (float)i;
    float o0[2], o1[2], o2[2];
    float oob = 0.0f;

#pragma unroll
    for (int k = 0; k < 2; ++k) {
        float cx  = k ? cx2.y : cx2.x;
        float cy  = k ? cy2.y : cy2.x;
        float m1v = k ? m12.y : m12.x;
        float m2v = k ? m22.y : m22.x;
        float fj  = (float)(j0 + k);

        float tot = m1v + m2v;
        float inv = 1.0f / tot;
        float m1n = m1v * inv, m2n = m2v * inv;

        float rx1 = (fi + cx) * 512.0f, ry1 = (fj + cy) * 512.0f;
        float rx2 = (fi - cx) * 512.0f, ry2 = (fj - cy) * 512.0f;

        // exact: (fi - |cx|)*512 == min(rx1, rx2) (f32 sub + pow2 mul are exact)
        bool fast = ((fi - fabsf(cx)) * 512.0f >= 510.999f)
                 && ((fj - fabsf(cy)) * 512.0f >= 510.999f);

        float r3[3];
        if (fast) {
            float dx1 = rx1 - 510.999f, dy1 = ry1 - 510.999f;
            float dx2 = rx2 - 510.999f, dy2 = ry2 - 510.999f;
            oob += dx1 * dx1 + dy1 * dy1 + dx2 * dx2 + dy2 * dy2;
            r3[0] = m1n * S1[0] + m2n * S2[0];
            r3[1] = m1n * S1[1] + m2n * S2[1];
            r3[2] = m1n * S1[2] + m2n * S2[2];
        } else {
            r3[0] = r3[1] = r3[2] = 0.0f;
            samp_gather(base1, rx1, ry1, m1n, r3, &oob);
            samp_gather(base2, rx2, ry2, m2n, r3, &oob);
        }
        o0[k] = r3[0]; o1[k] = r3[1]; o2[k] = r3[2];
    }

    *(float2*)(out + ob + pp)          = make_float2(o0[0], o0[1]);
    *(float2*)(out + ob + HW + pp)     = make_float2(o1[0], o1[1]);
    *(float2*)(out + ob + 2 * HW + pp) = make_float2(o2[0], o2[1]);

    // ---- block reduction of oob (f32 in-wave, f64 across waves) ----
    for (int off = 32; off > 0; off >>= 1)
        oob += __shfl_down(oob, off, 64);

    __shared__ float soob[BLOCK / 64];
    int lane = threadIdx.x & 63;
    int w    = threadIdx.x >> 6;
    if (lane == 0) soob[w] = oob;
    __syncthreads();
    if (threadIdx.x == 0)
        partials[blockIdx.x] = (double)soob[0] + (double)soob[1]
                             + (double)soob[2] + (double)soob[3];
}

__global__ void __launch_bounds__(BLOCK) reduce_kernel(
    const double* __restrict__ partials, int nparts,
    float* __restrict__ out_last, double scale)
{
    double s = 0.0;
    for (int i = threadIdx.x; i < nparts; i += BLOCK)
        s += partials[i];
    for (int off = 32; off > 0; off >>= 1)
        s += __shfl_down(s, off, 64);

    __shared__ double sm[BLOCK / 64];
    int lane = threadIdx.x & 63;
    int w    = threadIdx.x >> 6;
    if (lane == 0) sm[w] = s;
    __syncthreads();
    if (threadIdx.x == 0)
        *out_last = (float)((sm[0] + sm[1] + sm[2] + sm[3]) * scale);
}

extern "C" void kernel_launch(void* const* d_in, const int* in_sizes, int n_in,
                              void* d_out, int out_size, void* d_ws, size_t ws_size,
                              hipStream_t stream) {
    const float* im1 = (const float*)d_in[0];
    const float* im2 = (const float*)d_in[1];
    const float* C   = (const float*)d_in[2];
    const float* M1  = (const float*)d_in[3];
    const float* M2  = (const float*)d_in[4];
    float* out = (float*)d_out;
    double* ws = (double*)d_ws;

    int N = in_sizes[3] / HW;        // M1 is [N,1,H,W]
    int blocks = N * D;              // one row per block -> 8192

    vm_kernel<<<blocks, BLOCK, 0, stream>>>(im1, im2, C, M1, M2, out, ws);

    // loss = sum / (N*2*HW) / D^2 * 1e-4  (a and b share the mean count)
    double scale = 1.0 / ((double)N * 2.0 * (double)HW) / (double)HW * 1e-4;
    reduce_kernel<<<1, BLOCK, 0, stream>>>(ws, blocks, out + (out_size - 1), scale);
}